// Round 2
// 803.995 us; speedup vs baseline: 1.1967x; 1.1967x over previous
//
#include <hip/hip_runtime.h>

static constexpr int S  = 2048;
static constexpr int E  = 128;
static constexpr int V  = 50257;

typedef __attribute__((ext_vector_type(8))) short bf16x8;
typedef __attribute__((ext_vector_type(4))) float floatx4;

#define MF(a, b, c) __builtin_amdgcn_mfma_f32_16x16x32_bf16((a), (b), (c), 0, 0, 0)

// ---------------- fragment-ordered bf16 workspace geometry ----------------
// A-side (psi): 4 mats: 0=psi_r hi, 1=psi_r lo, 2=psi_i hi, 3=psi_i lo
// B-side (vocab): 6 mats: 0=pat_r hi, 1=pat_r lo, 2=pat_i hi, 3=pat_i lo, 4=W hi, 5=W lo
// Fragment order: [tile16][kchunk32][lane64][8 elems], elem (lane,j) =
//   src[tile*16 + (lane&15)][kc*32 + (lane>>4)*8 + j]
// so a wave's 16 B/lane load IS the mfma_f32_16x16x32_bf16 operand.
static constexpr int  RT       = S / 16;             // 128 row tiles
static constexpr int  NBLK     = (V + 63) / 64;      // 786 column blocks (64 cols)
static constexpr int  CT       = NBLK * 4;           // 3144 col tiles (padded to 50304)
static constexpr long A_MAT    = (long)RT * 4 * 64 * 8;   // 262144 shorts
static constexpr long B_MAT    = (long)CT * 4 * 64 * 8;   // 6438912 shorts
static constexpr long WS_SHORTS = 4 * A_MAT + 6 * B_MAT;
static constexpr long WS_BYTES  = WS_SHORTS * 2;          // 79,364,096 B

// Split fp32 into bf16 hi + bf16 lo (truncation split: exact to ~2^-16 rel).
__device__ __forceinline__ void split2(float x, unsigned short& hi, unsigned short& lo) {
    unsigned xb = __float_as_uint(x);
    hi = (unsigned short)(xb >> 16);
    float hf = __uint_as_float(xb & 0xFFFF0000u);
    lo = (unsigned short)(__float_as_uint(x - hf) >> 16);
}

__device__ __forceinline__ void cvt8(const float* v, bf16x8& hi, bf16x8& lo) {
    #pragma unroll
    for (int j = 0; j < 8; j++) {
        unsigned short h, l;
        split2(v[j], h, l);
        hi[j] = (short)h;
        lo[j] = (short)l;
    }
}

// ---------------- preprocessing: psi -> frag-ordered bf16 hi/lo ----------------
__global__ __launch_bounds__(256)
void pre_a(const float* __restrict__ psi_r, const float* __restrict__ psi_i,
           short* __restrict__ ws)
{
    const int t    = blockIdx.x * 256 + threadIdx.x;   // 0..32767 (RT*4*64)
    const int lane = t & 63;
    const int kc   = (t >> 6) & 3;
    const int rt   = t >> 8;
    const int row  = rt * 16 + (lane & 15);
    const int k0   = kc * 32 + (lane >> 4) * 8;

    float v[8];
    const float* p = psi_r + (long)row * E + k0;
    #pragma unroll
    for (int j = 0; j < 8; j++) v[j] = p[j];
    bf16x8 hi, lo; cvt8(v, hi, lo);
    *(bf16x8*)(ws + 0 * A_MAT + (long)t * 8) = hi;
    *(bf16x8*)(ws + 1 * A_MAT + (long)t * 8) = lo;

    p = psi_i + (long)row * E + k0;
    #pragma unroll
    for (int j = 0; j < 8; j++) v[j] = p[j];
    cvt8(v, hi, lo);
    *(bf16x8*)(ws + 2 * A_MAT + (long)t * 8) = hi;
    *(bf16x8*)(ws + 3 * A_MAT + (long)t * 8) = lo;
}

// ---------------- preprocessing: patterns/W -> frag-ordered bf16 hi/lo ----------------
__global__ __launch_bounds__(256)
void pre_b(const float* __restrict__ pat_r, const float* __restrict__ pat_i,
           const float* __restrict__ Wm, short* __restrict__ ws)
{
    const int t    = blockIdx.x * 256 + threadIdx.x;   // 0..804863 (CT*4*64)
    const int lane = t & 63;
    const int kc   = (t >> 6) & 3;
    const int ct   = t >> 8;
    const int row  = ct * 16 + (lane & 15);            // vocab row (output column)
    const int k0   = kc * 32 + (lane >> 4) * 8;
    const bool ok  = row < V;

    short* B0 = ws + 4 * A_MAT;
    const float* srcs[3] = { pat_r, pat_i, Wm };
    #pragma unroll
    for (int s = 0; s < 3; s++) {
        float v[8];
        if (ok) {
            const float* p = srcs[s] + (long)row * E + k0;
            #pragma unroll
            for (int j = 0; j < 8; j++) v[j] = p[j];
        } else {
            #pragma unroll
            for (int j = 0; j < 8; j++) v[j] = 0.f;    // pad cols: zero products
        }
        bf16x8 hi, lo; cvt8(v, hi, lo);
        *(bf16x8*)(B0 + (long)(2 * s)     * B_MAT + (long)t * 8) = hi;
        *(bf16x8*)(B0 + (long)(2 * s + 1) * B_MAT + (long)t * 8) = lo;
    }
}

// ---------------- main: LDS-free, barrier-free MFMA kernel ----------------
// Block: 4 waves, 2M x 2N. Wave tile: 64 rows (mi=4) x 32 cols (ni=2).
// Block tile: 128 x 64. Grid: (16 M-blocks fastest) x (786 N-blocks) so that
// the 16 blocks sharing one B tile dispatch back-to-back (L2/L3 locality).
__global__ __launch_bounds__(256, 2)
void interference_mfma(const short* __restrict__ ws,
                       const float* __restrict__ bias,
                       float* __restrict__ out)
{
    const int tid  = threadIdx.x;
    const int wave = tid >> 6;
    const int lane = tid & 63;
    const int quad = lane >> 4;
    const int r16  = lane & 15;
    const int wm   = wave >> 1;
    const int wn   = wave & 1;
    const int mb   = blockIdx.x;     // 0..15
    const int nb   = blockIdx.y;     // 0..785

    const short* Ah = ws + 0 * A_MAT;   // psi_r hi
    const short* Al = ws + 1 * A_MAT;   // psi_r lo
    const short* Ih = ws + 2 * A_MAT;   // psi_i hi
    const short* Il = ws + 3 * A_MAT;   // psi_i lo
    const short* Bm = ws + 4 * A_MAT;   // 6 vocab mats

    const int rt0 = mb * 8 + wm * 4;
    const int ct0 = nb * 4 + wn * 2;

    floatx4 Cr[4][2], Ci[4][2], Cl[4][2];
    #pragma unroll
    for (int mi = 0; mi < 4; mi++)
        #pragma unroll
        for (int ni = 0; ni < 2; ni++) {
            Cr[mi][ni] = floatx4{0.f, 0.f, 0.f, 0.f};
            Ci[mi][ni] = floatx4{0.f, 0.f, 0.f, 0.f};
            Cl[mi][ni] = floatx4{0.f, 0.f, 0.f, 0.f};
        }

    for (int kc = 0; kc < 4; kc++) {
        // B fragments: 12 coalesced dwordx4 loads, live for the whole chunk
        bf16x8 fB[6][2];
        #pragma unroll
        for (int m = 0; m < 6; m++)
            #pragma unroll
            for (int ni = 0; ni < 2; ni++)
                fB[m][ni] = *(const bf16x8*)(Bm + (long)m * B_MAT +
                                             (((long)(ct0 + ni) * 4 + kc) * 64 + lane) * 8);
        #pragma unroll
        for (int mi = 0; mi < 4; mi++) {
            const long ao = (((long)(rt0 + mi) * 4 + kc) * 64 + lane) * 8;
            bf16x8 ah = *(const bf16x8*)(Ah + ao);
            bf16x8 al = *(const bf16x8*)(Al + ao);
            bf16x8 ih = *(const bf16x8*)(Ih + ao);
            bf16x8 il = *(const bf16x8*)(Il + ao);
            #pragma unroll
            for (int ni = 0; ni < 2; ni++) {
                // C_r += psi_r*pat_r + psi_i*pat_i   (3-product split each)
                Cr[mi][ni] = MF(ah, fB[0][ni], Cr[mi][ni]);
                Cr[mi][ni] = MF(ah, fB[1][ni], Cr[mi][ni]);
                Cr[mi][ni] = MF(al, fB[0][ni], Cr[mi][ni]);
                Cr[mi][ni] = MF(ih, fB[2][ni], Cr[mi][ni]);
                Cr[mi][ni] = MF(ih, fB[3][ni], Cr[mi][ni]);
                Cr[mi][ni] = MF(il, fB[2][ni], Cr[mi][ni]);
                // C_i += psi_r*pat_i
                Ci[mi][ni] = MF(ah, fB[2][ni], Ci[mi][ni]);
                Ci[mi][ni] = MF(ah, fB[3][ni], Ci[mi][ni]);
                Ci[mi][ni] = MF(al, fB[2][ni], Ci[mi][ni]);
                // C_lin += psi_r*W
                Cl[mi][ni] = MF(ah, fB[4][ni], Cl[mi][ni]);
                Cl[mi][ni] = MF(ah, fB[5][ni], Cl[mi][ni]);
                Cl[mi][ni] = MF(al, fB[4][ni], Cl[mi][ni]);
            }
            // C_i += (-psi_i)*pat_r  (bf16 sign-bit flip in-register)
            ih = ih ^ (short)0x8000;
            il = il ^ (short)0x8000;
            #pragma unroll
            for (int ni = 0; ni < 2; ni++) {
                Ci[mi][ni] = MF(ih, fB[0][ni], Ci[mi][ni]);
                Ci[mi][ni] = MF(ih, fB[1][ni], Ci[mi][ni]);
                Ci[mi][ni] = MF(il, fB[0][ni], Ci[mi][ni]);
            }
        }
    }

    // ---- epilogue: out = Cr^2 + Ci^2 + Cl + b
    #pragma unroll
    for (int ni = 0; ni < 2; ni++) {
        const int col = nb * 64 + wn * 32 + ni * 16 + r16;
        if (col < V) {
            const float bv = bias[col];
            #pragma unroll
            for (int mi = 0; mi < 4; mi++) {
                const int rbase = mb * 128 + wm * 64 + mi * 16 + quad * 4;
                #pragma unroll
                for (int r = 0; r < 4; r++) {
                    float cr = Cr[mi][ni][r];
                    float ci = Ci[mi][ni][r];
                    float cl = Cl[mi][ni][r];
                    out[(long)(rbase + r) * V + col] = cr * cr + ci * ci + cl + bv;
                }
            }
        }
    }
}

// ================= fallback (previous verified kernel) =================
static constexpr int MB = 128;
static constexpr int NB = 48;
static constexpr int KP = 40;

__global__ __launch_bounds__(256, 2)
void interference_kernel(const float* __restrict__ psi_r,
                         const float* __restrict__ psi_i,
                         const float* __restrict__ pat_r,
                         const float* __restrict__ pat_i,
                         const float* __restrict__ Wm,
                         const float* __restrict__ bias,
                         float* __restrict__ out)
{
    __shared__ short smem[4 * MB * KP + 6 * NB * KP];
    short* sA = smem;
    short* sB = smem + 4 * MB * KP;

    const int tid  = threadIdx.x;
    const int wave = tid >> 6;
    const int lane = tid & 63;
    const int quad = lane >> 4;
    const int r16  = lane & 15;

    const int m0 = blockIdx.y * MB;
    const int v0 = blockIdx.x * NB;

    floatx4 Cr[2][3], Ci[2][3], Cl[2][3];
    #pragma unroll
    for (int mi = 0; mi < 2; mi++)
        #pragma unroll
        for (int ni = 0; ni < 3; ni++) {
            Cr[mi][ni] = floatx4{0.f, 0.f, 0.f, 0.f};
            Ci[mi][ni] = floatx4{0.f, 0.f, 0.f, 0.f};
            Cl[mi][ni] = floatx4{0.f, 0.f, 0.f, 0.f};
        }

    for (int chunk = 0; chunk < E / 32; chunk++) {
        const int kc = chunk * 32;
        #pragma unroll
        for (int i = 0; i < 8; i++) {
            int idx = tid + i * 256;
            int src = idx >> 10;
            int rem = idx & 1023;
            int row = rem >> 3;
            int kq  = rem & 7;
            const float* bsrc = src ? psi_i : psi_r;
            const float4 x = *(const float4*)(bsrc + (m0 + row) * E + kc + kq * 4);
            unsigned short h0, h1, h2, h3, l0, l1, l2, l3;
            split2(x.x, h0, l0); split2(x.y, h1, l1);
            split2(x.z, h2, l2); split2(x.w, h3, l3);
            int offh = ((src * 2) * MB + row) * KP + kq * 4;
            int offl = offh + MB * KP;
            uint2 uh = make_uint2((unsigned)h0 | ((unsigned)h1 << 16),
                                  (unsigned)h2 | ((unsigned)h3 << 16));
            uint2 ul = make_uint2((unsigned)l0 | ((unsigned)l1 << 16),
                                  (unsigned)l2 | ((unsigned)l3 << 16));
            *(uint2*)(sA + offh) = uh;
            *(uint2*)(sA + offl) = ul;
        }
        #pragma unroll
        for (int i = 0; i < 5; i++) {
            int idx = tid + i * 256;
            if (idx < 1152) {
                int src = idx / 384;
                int rem = idx - src * 384;
                int row = rem >> 3;
                int kq  = rem & 7;
                int vv  = v0 + row; if (vv > V - 1) vv = V - 1;
                const float* bsrc = (src == 0) ? pat_r : ((src == 1) ? pat_i : Wm);
                const float4 x = *(const float4*)(bsrc + vv * E + kc + kq * 4);
                unsigned short h0, h1, h2, h3, l0, l1, l2, l3;
                split2(x.x, h0, l0); split2(x.y, h1, l1);
                split2(x.z, h2, l2); split2(x.w, h3, l3);
                int offh = ((src * 2) * NB + row) * KP + kq * 4;
                int offl = offh + NB * KP;
                uint2 uh = make_uint2((unsigned)h0 | ((unsigned)h1 << 16),
                                      (unsigned)h2 | ((unsigned)h3 << 16));
                uint2 ul = make_uint2((unsigned)l0 | ((unsigned)l1 << 16),
                                      (unsigned)l2 | ((unsigned)l3 << 16));
                *(uint2*)(sB + offh) = uh;
                *(uint2*)(sB + offl) = ul;
            }
        }
        __syncthreads();

        bf16x8 fB[6][3];
        #pragma unroll
        for (int bm = 0; bm < 6; bm++)
            #pragma unroll
            for (int ni = 0; ni < 3; ni++)
                fB[bm][ni] = *(const bf16x8*)(sB + (bm * NB + ni * 16 + r16) * KP + quad * 8);

        #pragma unroll
        for (int mi = 0; mi < 2; mi++) {
            const int ab = (wave * 32 + mi * 16 + r16) * KP + quad * 8;
            bf16x8 Prh = *(const bf16x8*)(sA + ab);
            bf16x8 Prl = *(const bf16x8*)(sA + ab + MB * KP);
            bf16x8 Pih = *(const bf16x8*)(sA + ab + 2 * MB * KP);
            bf16x8 Pil = *(const bf16x8*)(sA + ab + 3 * MB * KP);
            #pragma unroll
            for (int ni = 0; ni < 3; ni++) {
                Cr[mi][ni] = MF(Prh, fB[0][ni], Cr[mi][ni]);
                Cr[mi][ni] = MF(Prh, fB[1][ni], Cr[mi][ni]);
                Cr[mi][ni] = MF(Prl, fB[0][ni], Cr[mi][ni]);
                Cr[mi][ni] = MF(Pih, fB[2][ni], Cr[mi][ni]);
                Cr[mi][ni] = MF(Pih, fB[3][ni], Cr[mi][ni]);
                Cr[mi][ni] = MF(Pil, fB[2][ni], Cr[mi][ni]);
                Ci[mi][ni] = MF(Prh, fB[2][ni], Ci[mi][ni]);
                Ci[mi][ni] = MF(Prh, fB[3][ni], Ci[mi][ni]);
                Ci[mi][ni] = MF(Prl, fB[2][ni], Ci[mi][ni]);
                Cl[mi][ni] = MF(Prh, fB[4][ni], Cl[mi][ni]);
                Cl[mi][ni] = MF(Prh, fB[5][ni], Cl[mi][ni]);
                Cl[mi][ni] = MF(Prl, fB[4][ni], Cl[mi][ni]);
            }
            Pih = Pih ^ (short)0x8000;
            Pil = Pil ^ (short)0x8000;
            #pragma unroll
            for (int ni = 0; ni < 3; ni++) {
                Ci[mi][ni] = MF(Pih, fB[0][ni], Ci[mi][ni]);
                Ci[mi][ni] = MF(Pih, fB[1][ni], Ci[mi][ni]);
                Ci[mi][ni] = MF(Pil, fB[0][ni], Ci[mi][ni]);
            }
        }
        __syncthreads();
    }

    #pragma unroll
    for (int ni = 0; ni < 3; ni++) {
        const int col = v0 + ni * 16 + r16;
        if (col < V) {
            const float bv = bias[col];
            #pragma unroll
            for (int mi = 0; mi < 2; mi++) {
                const int rbase = m0 + wave * 32 + mi * 16 + quad * 4;
                #pragma unroll
                for (int r = 0; r < 4; r++) {
                    float cr = Cr[mi][ni][r];
                    float ci = Ci[mi][ni][r];
                    float cl = Cl[mi][ni][r];
                    out[(long)(rbase + r) * V + col] = cr * cr + ci * ci + cl + bv;
                }
            }
        }
    }
}

extern "C" void kernel_launch(void* const* d_in, const int* in_sizes, int n_in,
                              void* d_out, int out_size, void* d_ws, size_t ws_size,
                              hipStream_t stream) {
    const float* psi_r = (const float*)d_in[0];
    const float* psi_i = (const float*)d_in[1];
    const float* pat_r = (const float*)d_in[2];
    const float* pat_i = (const float*)d_in[3];
    const float* Wm    = (const float*)d_in[4];
    const float* b     = (const float*)d_in[5];
    float* out = (float*)d_out;

    if (d_ws && ws_size >= (size_t)WS_BYTES) {
        short* ws = (short*)d_ws;
        pre_a<<<RT * 4 * 64 / 256, 256, 0, stream>>>(psi_r, psi_i, ws);          // 128 blocks
        pre_b<<<CT * 4 * 64 / 256, 256, 0, stream>>>(pat_r, pat_i, Wm, ws);      // 3144 blocks
        interference_mfma<<<dim3(S / 128, NBLK), 256, 0, stream>>>(ws, b, out);  // 16 x 786
    } else {
        dim3 grid((V + NB - 1) / NB, S / MB);
        interference_kernel<<<grid, dim3(256), 0, stream>>>(psi_r, psi_i, pat_r, pat_i, Wm, b, out);
    }
}